// Round 10
// baseline (356.770 us; speedup 1.0000x reference)
//
#include <hip/hip_runtime.h>

#define N_NODES 10000
#define N_EDGES 320000
#define N_CAND  100000
#define HID     256
#define N_MP    3
#define N_ATYPE 100

typedef short bf16x8 __attribute__((ext_vector_type(8)));
typedef float f32x4  __attribute__((ext_vector_type(4)));

static __device__ __forceinline__ float relu_f(float x) { return x > 0.f ? x : 0.f; }

// split fp32 -> bf16 hi (truncate) + bf16 lo (RNE of residual); a ~= hi + lo to 2^-17
static __device__ __forceinline__ void split_bf16(float s, unsigned short& hi,
                                                  unsigned short& lo)
{
    unsigned u = __float_as_uint(s);
    hi = (unsigned short)(u >> 16);
    float rem = s - __uint_as_float(u & 0xffff0000u);
    unsigned v = __float_as_uint(rem);
    unsigned r = v + 0x7fffu + ((v >> 16) & 1u);   // RNE to bf16
    lo = (unsigned short)(r >> 16);
}

// ---------------------------------------------------------------------------
// fp32 GEMM (kept only for tiny E0 = atom_embed @ atom_W + atom_b)
// ---------------------------------------------------------------------------
__global__ __launch_bounds__(256) void k_gemm(
    const float* __restrict__ A, const float* __restrict__ B,
    const float* __restrict__ bias, float* __restrict__ C,
    int M, int doRelu)
{
    __shared__ float As[32][64];
    __shared__ float Bs[32][64];
    int tid = threadIdx.x;
    int tx = tid & 15, ty = tid >> 4;
    int mb = blockIdx.x * 64, nb = blockIdx.y * 64;
    float acc[4][4] = {};
    for (int k0 = 0; k0 < 256; k0 += 32) {
        #pragma unroll
        for (int p = 0; p < 2; ++p) {
            int flat = p * 256 + tid;
            int row = flat >> 3, kc = flat & 7;
            float4 av = make_float4(0.f, 0.f, 0.f, 0.f);
            if (mb + row < M)
                av = *(const float4*)(A + (size_t)(mb + row) * 256 + k0 + kc * 4);
            int sc = row ^ (kc << 2);
            As[kc * 4 + 0][sc] = av.x; As[kc * 4 + 1][sc] = av.y;
            As[kc * 4 + 2][sc] = av.z; As[kc * 4 + 3][sc] = av.w;
        }
        #pragma unroll
        for (int p = 0; p < 2; ++p) {
            int flat = p * 256 + tid;
            int row = flat >> 4, c = flat & 15;
            *(float4*)(&Bs[row][c * 4]) =
                *(const float4*)(B + (size_t)(k0 + row) * 256 + nb + c * 4);
        }
        __syncthreads();
        #pragma unroll 16
        for (int k = 0; k < 32; ++k) {
            float4 a4 = *(const float4*)(&As[k][(ty * 4) ^ ((k >> 2) << 2)]);
            float4 b4 = *(const float4*)(&Bs[k][tx * 4]);
            float a[4] = {a4.x, a4.y, a4.z, a4.w};
            float b[4] = {b4.x, b4.y, b4.z, b4.w};
            #pragma unroll
            for (int i = 0; i < 4; ++i)
                #pragma unroll
                for (int j = 0; j < 4; ++j)
                    acc[i][j] = fmaf(a[i], b[j], acc[i][j]);
        }
        __syncthreads();
    }
    #pragma unroll
    for (int i = 0; i < 4; ++i) {
        int row = mb + ty * 4 + i;
        if (row >= M) continue;
        float r[4];
        #pragma unroll
        for (int j = 0; j < 4; ++j) {
            r[j] = acc[i][j] + (bias ? bias[nb + tx * 4 + j] : 0.f);
            if (doRelu) r[j] = relu_f(r[j]);
        }
        *(float4*)(C + (size_t)row * 256 + nb + tx * 4) =
            make_float4(r[0], r[1], r[2], r[3]);
    }
}

// ---------------------------------------------------------------------------
// Weight prep: W[k][n] fp32 -> WT_hi/WT_lo [n][k] split-bf16.
// mats 0..2 = conv_W, 3..4 = s_W1 halves. 320 blocks x 256 threads.
// ---------------------------------------------------------------------------
__global__ __launch_bounds__(256) void k_prep_w(
    const float* __restrict__ conv_W, const float* __restrict__ s_W1,
    unsigned short* __restrict__ WTh, unsigned short* __restrict__ WTl)
{
    int bid = blockIdx.x;
    int mat = bid >> 6;                          // 0..4
    int id  = (bid & 63) * 256 + threadIdx.x;    // 0..16383
    int k   = id >> 6;                           // 0..255
    int n4  = id & 63;                           // 0..63
    const float* src = (mat < 3) ? conv_W + (size_t)mat * 65536
                                 : s_W1 + (size_t)(mat - 3) * 65536;
    float4 w = *(const float4*)(src + (size_t)k * 256 + n4 * 4);
    float ws[4] = {w.x, w.y, w.z, w.w};
    #pragma unroll
    for (int j = 0; j < 4; ++j) {
        unsigned short hi, lo;
        split_bf16(ws[j], hi, lo);
        size_t idx = (size_t)mat * 65536 + (size_t)(n4 * 4 + j) * 256 + k;
        WTh[idx] = hi;
        WTl[idx] = lo;
    }
}

// h fp32 -> Ah/Al split-bf16 (for the pq GEMM's A operand). 2500 x 256.
__global__ __launch_bounds__(256) void k_split(
    const float* __restrict__ h, unsigned short* __restrict__ Ah,
    unsigned short* __restrict__ Al)
{
    int i = blockIdx.x * 256 + threadIdx.x;      // float4 index, 640000 total
    float4 v = ((const float4*)h)[i];
    float vs[4] = {v.x, v.y, v.z, v.w};
    unsigned short hs[4], ls[4];
    #pragma unroll
    for (int j = 0; j < 4; ++j) split_bf16(vs[j], hs[j], ls[j]);
    ushort4 hv = make_ushort4(hs[0], hs[1], hs[2], hs[3]);
    ushort4 lv = make_ushort4(ls[0], ls[1], ls[2], ls[3]);
    ((ushort4*)Ah)[i] = hv;
    ((ushort4*)Al)[i] = lv;
}

// ---------------------------------------------------------------------------
// bf16x3 MFMA tile: one wave computes C[32x32] at (mb,nb).
// A as split-bf16 [M][256] (hi,lo); W as split-bf16 transposed [256 n][256 k].
// C = (Ah+Al)@(Wh+Wl) ~= Ah Wh + Ah Wl + Al Wh  (fp32 accum).
// Fragment addressing: lane li=l&15, g=l>>4; A-frag = A[row][k0+g*8 .. +8]
// (16B contiguous); B-frag = WT[col][k0+g*8 .. +8]. No LDS, no barriers.
// C/D map (m89): col = l&15, row = g*4 + reg.
// ---------------------------------------------------------------------------
static __device__ __forceinline__ void mfma_tile(
    const unsigned short* __restrict__ Ah, const unsigned short* __restrict__ Al,
    const unsigned short* __restrict__ Wh, const unsigned short* __restrict__ Wl,
    const float* __restrict__ bias, const float* __restrict__ scale,
    float* __restrict__ C, int M, int mb, int nb, int doRelu)
{
    int l  = threadIdx.x & 63;
    int li = l & 15;
    int g  = l >> 4;

    int r0 = mb + li;       if (r0 >= M) r0 = M - 1;   // clamp (stores guarded)
    int r1 = mb + 16 + li;  if (r1 >= M) r1 = M - 1;
    int c0 = nb + li;
    int c1 = nb + 16 + li;

    const unsigned short* pA0h = Ah + (size_t)r0 * 256 + g * 8;
    const unsigned short* pA1h = Ah + (size_t)r1 * 256 + g * 8;
    const unsigned short* pA0l = Al + (size_t)r0 * 256 + g * 8;
    const unsigned short* pA1l = Al + (size_t)r1 * 256 + g * 8;
    const unsigned short* pB0h = Wh + (size_t)c0 * 256 + g * 8;
    const unsigned short* pB1h = Wh + (size_t)c1 * 256 + g * 8;
    const unsigned short* pB0l = Wl + (size_t)c0 * 256 + g * 8;
    const unsigned short* pB1l = Wl + (size_t)c1 * 256 + g * 8;

    f32x4 acc00 = {0.f, 0.f, 0.f, 0.f};
    f32x4 acc01 = {0.f, 0.f, 0.f, 0.f};
    f32x4 acc10 = {0.f, 0.f, 0.f, 0.f};
    f32x4 acc11 = {0.f, 0.f, 0.f, 0.f};

    #pragma unroll
    for (int ks = 0; ks < 8; ++ks) {
        int o = ks * 32;                        // ushort offset per k-step
        bf16x8 a0h = *(const bf16x8*)(pA0h + o);
        bf16x8 a1h = *(const bf16x8*)(pA1h + o);
        bf16x8 a0l = *(const bf16x8*)(pA0l + o);
        bf16x8 a1l = *(const bf16x8*)(pA1l + o);
        bf16x8 b0h = *(const bf16x8*)(pB0h + o);
        bf16x8 b1h = *(const bf16x8*)(pB1h + o);
        bf16x8 b0l = *(const bf16x8*)(pB0l + o);
        bf16x8 b1l = *(const bf16x8*)(pB1l + o);

        acc00 = __builtin_amdgcn_mfma_f32_16x16x32_bf16(a0h, b0h, acc00, 0, 0, 0);
        acc01 = __builtin_amdgcn_mfma_f32_16x16x32_bf16(a0h, b1h, acc01, 0, 0, 0);
        acc10 = __builtin_amdgcn_mfma_f32_16x16x32_bf16(a1h, b0h, acc10, 0, 0, 0);
        acc11 = __builtin_amdgcn_mfma_f32_16x16x32_bf16(a1h, b1h, acc11, 0, 0, 0);

        acc00 = __builtin_amdgcn_mfma_f32_16x16x32_bf16(a0h, b0l, acc00, 0, 0, 0);
        acc01 = __builtin_amdgcn_mfma_f32_16x16x32_bf16(a0h, b1l, acc01, 0, 0, 0);
        acc10 = __builtin_amdgcn_mfma_f32_16x16x32_bf16(a1h, b0l, acc10, 0, 0, 0);
        acc11 = __builtin_amdgcn_mfma_f32_16x16x32_bf16(a1h, b1l, acc11, 0, 0, 0);

        acc00 = __builtin_amdgcn_mfma_f32_16x16x32_bf16(a0l, b0h, acc00, 0, 0, 0);
        acc01 = __builtin_amdgcn_mfma_f32_16x16x32_bf16(a0l, b1h, acc01, 0, 0, 0);
        acc10 = __builtin_amdgcn_mfma_f32_16x16x32_bf16(a1l, b0h, acc10, 0, 0, 0);
        acc11 = __builtin_amdgcn_mfma_f32_16x16x32_bf16(a1l, b1h, acc11, 0, 0, 0);
    }

    // epilogue + store (C/D: col = l&15 per ct, row = g*4 + j per rt)
    #pragma unroll
    for (int rt = 0; rt < 2; ++rt) {
        #pragma unroll
        for (int ct = 0; ct < 2; ++ct) {
            f32x4 a = rt ? (ct ? acc11 : acc10) : (ct ? acc01 : acc00);
            int col = nb + ct * 16 + li;
            float bv = bias ? bias[col] : 0.f;
            #pragma unroll
            for (int j = 0; j < 4; ++j) {
                int row = mb + rt * 16 + g * 4 + j;
                if (row >= M) continue;
                float v = a[j] + bv;
                if (doRelu) v = relu_f(v);
                if (scale) v *= scale[row];
                C[(size_t)row * 256 + col] = v;
            }
        }
    }
}

// conv GEMM: grid 2560 x 64thr. l=bid&7 (XCD), y=(bid>>3)&7, gx=bid>>6, x=gx*8+l
__global__ __launch_bounds__(64) void k_gemm_conv_mfma(
    const unsigned short* __restrict__ Ah, const unsigned short* __restrict__ Al,
    const unsigned short* __restrict__ Wh, const unsigned short* __restrict__ Wl,
    const float* __restrict__ bias, const float* __restrict__ scale,
    float* __restrict__ C, int M)
{
    int bid = blockIdx.x;
    int l = bid & 7;
    int r = bid >> 3;            // 0..319
    int y = r & 7;
    int gx = r >> 3;             // 0..39
    int x = gx * 8 + l;
    if (x * 32 >= M) return;
    mfma_tile(Ah, Al, Wh, Wl, bias, scale, C, M, x * 32, y * 32, 1);
}

// pq GEMM: grid 5120 x 64thr. half selects W1 half + P/Q output.
__global__ __launch_bounds__(64) void k_gemm_pq_mfma(
    const unsigned short* __restrict__ Ah, const unsigned short* __restrict__ Al,
    const unsigned short* __restrict__ WTh, const unsigned short* __restrict__ WTl,
    float* __restrict__ P, float* __restrict__ Q, int M)
{
    int bid = blockIdx.x;
    int l = bid & 7;
    int r = bid >> 3;            // 0..639
    int y = r & 7;
    int t = r >> 3;              // 0..79
    int half = t & 1;
    int gx = t >> 1;             // 0..39
    int x = gx * 8 + l;
    if (x * 32 >= M) return;
    const unsigned short* wh = WTh + (size_t)(3 + half) * 65536;
    const unsigned short* wl = WTl + (size_t)(3 + half) * 65536;
    mfma_tile(Ah, Al, wh, wl, nullptr, nullptr, half ? Q : P, M, x * 32, y * 32, 0);
}

// ---------------------------------------------------------------------------
__global__ void k_hist(const int* __restrict__ ei,
                       int* __restrict__ dout, int* __restrict__ din)
{
    int e = blockIdx.x * blockDim.x + threadIdx.x;
    if (e >= N_EDGES) return;
    atomicAdd(&dout[ei[e]], 1);
    atomicAdd(&din[ei[N_EDGES + e]], 1);
}

__global__ void k_norm(const int* __restrict__ dout, const int* __restrict__ din,
                       float* __restrict__ ns, float* __restrict__ nd)
{
    int i = blockIdx.x * blockDim.x + threadIdx.x;
    if (i >= N_NODES) return;
    int o = dout[i], in = din[i];
    ns[i] = (o  > 0) ? (1.0f / sqrtf((float)o))  : 0.f;
    nd[i] = (in > 0) ? (1.0f / sqrtf((float)in)) : 0.f;
}

// h0[node][:] = E0[atom_types[node]][:] * ns[node]
__global__ __launch_bounds__(256) void k_h0(const int* __restrict__ types,
                                            const float* __restrict__ E0,
                                            const float* __restrict__ ns,
                                            float* __restrict__ h)
{
    int node = blockIdx.x * 4 + (threadIdx.x >> 6);
    int lane = threadIdx.x & 63;
    if (node >= N_NODES) return;
    int t = types[node];
    float s = ns[node];
    float4 v = ((const float4*)E0)[t * 64 + lane];
    v.x *= s; v.y *= s; v.z *= s; v.w *= s;
    ((float4*)h)[node * 64 + lane] = v;
}

__global__ __launch_bounds__(1024) void k_scan(const int* __restrict__ deg,
                                               int* __restrict__ off, int n)
{
    __shared__ int part[1024];
    int t = threadIdx.x;
    int chunk = (n + 1023) / 1024;
    int base = t * chunk;
    int s = 0;
    for (int i = 0; i < chunk; ++i) {
        int idx = base + i;
        if (idx < n) s += deg[idx];
    }
    part[t] = s;
    __syncthreads();
    for (int d = 1; d < 1024; d <<= 1) {
        int v = (t >= d) ? part[t - d] : 0;
        __syncthreads();
        part[t] += v;
        __syncthreads();
    }
    int run = (t == 0) ? 0 : part[t - 1];
    if (t == 0) off[0] = 0;
    for (int i = 0; i < chunk; ++i) {
        int idx = base + i;
        if (idx < n) { run += deg[idx]; off[idx + 1] = run; }
    }
}

__global__ void k_fill(const int* __restrict__ ei, const int* __restrict__ off,
                       int* __restrict__ cur, int* __restrict__ csr)
{
    int e = blockIdx.x * blockDim.x + threadIdx.x;
    if (e >= N_EDGES) return;
    int d = ei[N_EDGES + e];
    int p = off[d] + atomicAdd(&cur[d], 1);
    csr[p] = ei[e];
}

// ---------------------------------------------------------------------------
// Persistent column-chunked aggregation (XCD-local h stripes), unroll-8.
// Writes split-bf16 (Ah, Al) directly -- the only consumer is the MFMA GEMM.
// ---------------------------------------------------------------------------
__global__ __launch_bounds__(256) void k_agg(
    const float* __restrict__ h, const float* __restrict__ nd,
    const int* __restrict__ off, const int* __restrict__ csr,
    unsigned short* __restrict__ Ah, unsigned short* __restrict__ Al)
{
    int bid  = blockIdx.x;
    int slot = bid & 7;
    int c    = slot >> 1;
    int p    = ((bid >> 3) << 1) | (slot & 1);
    int wave = threadIdx.x >> 6;
    int lane = threadIdx.x & 63;
    int wi   = p * 4 + wave;
    int col  = c * 64 + lane;

    for (int node = wi; node < N_NODES; node += 2048) {
        int s0 = off[node], s1 = off[node + 1];
        float a0 = 0.f, a1 = 0.f, a2 = 0.f, a3 = 0.f;
        float a4 = 0.f, a5 = 0.f, a6 = 0.f, a7 = 0.f;
        int e = s0;
        for (; e + 8 <= s1; e += 8) {
            int i0 = csr[e],     i1 = csr[e + 1], i2 = csr[e + 2], i3 = csr[e + 3];
            int i4 = csr[e + 4], i5 = csr[e + 5], i6 = csr[e + 6], i7 = csr[e + 7];
            float v0 = h[(size_t)i0 * 256 + col];
            float v1 = h[(size_t)i1 * 256 + col];
            float v2 = h[(size_t)i2 * 256 + col];
            float v3 = h[(size_t)i3 * 256 + col];
            float v4 = h[(size_t)i4 * 256 + col];
            float v5 = h[(size_t)i5 * 256 + col];
            float v6 = h[(size_t)i6 * 256 + col];
            float v7 = h[(size_t)i7 * 256 + col];
            a0 += v0; a1 += v1; a2 += v2; a3 += v3;
            a4 += v4; a5 += v5; a6 += v6; a7 += v7;
        }
        for (; e < s1; ++e)
            a0 += h[(size_t)csr[e] * 256 + col];
        float s = (((a0 + a1) + (a2 + a3)) + ((a4 + a5) + (a6 + a7))) * nd[node];
        unsigned short hi, lo;
        split_bf16(s, hi, lo);
        Ah[(size_t)node * 256 + col] = hi;
        Al[(size_t)node * 256 + col] = lo;
    }
}

// ---------------------------------------------------------------------------
// Scoring: 8 chunks x 32 cols, chunk = bid&7 -> XCD-local P/Q stripes.
// ---------------------------------------------------------------------------
__global__ __launch_bounds__(256) void k_score_part(
    const int* __restrict__ cand, const float* __restrict__ P,
    const float* __restrict__ Q, const float* __restrict__ b1,
    const float* __restrict__ W2, float* __restrict__ part)
{
    int bid = blockIdx.x;
    int c   = bid & 7;
    int grp = bid >> 3;
    int cd  = grp * 256 + threadIdx.x;
    if (cd >= N_CAND) return;

    int u = cand[2 * cd];
    int v = cand[2 * cd + 1];
    const float4* P4 = (const float4*)P;
    const float4* Q4 = (const float4*)Q;
    const float4* B4 = (const float4*)b1;
    const float4* W4 = (const float4*)W2;
    size_t pb = (size_t)u * 64 + c * 8;
    size_t qb = (size_t)v * 64 + c * 8;

    float4 p[8], q[8];
    #pragma unroll
    for (int i = 0; i < 8; ++i) p[i] = P4[pb + i];
    #pragma unroll
    for (int i = 0; i < 8; ++i) q[i] = Q4[qb + i];

    float acc = 0.f;
    #pragma unroll
    for (int i = 0; i < 8; ++i) {
        float4 b = B4[c * 8 + i];
        float4 w = W4[c * 8 + i];
        acc = fmaf(relu_f(p[i].x + q[i].x + b.x), w.x, acc);
        acc = fmaf(relu_f(p[i].y + q[i].y + b.y), w.y, acc);
        acc = fmaf(relu_f(p[i].z + q[i].z + b.z), w.z, acc);
        acc = fmaf(relu_f(p[i].w + q[i].w + b.w), w.w, acc);
    }
    part[(size_t)c * N_CAND + cd] = acc;
}

__global__ void k_sred(const float* __restrict__ part,
                       const float* __restrict__ b2, float* __restrict__ out)
{
    int i = blockIdx.x * 256 + threadIdx.x;
    if (i >= N_CAND) return;
    float s = b2[0];
    #pragma unroll
    for (int c = 0; c < 8; ++c) s += part[(size_t)c * N_CAND + i];
    out[i] = s;
}

// ---------------------------------------------------------------------------
extern "C" void kernel_launch(void* const* d_in, const int* in_sizes, int n_in,
                              void* d_out, int out_size, void* d_ws, size_t ws_size,
                              hipStream_t stream)
{
    const int*   atom_types = (const int*)d_in[0];
    const int*   edge_index = (const int*)d_in[2];
    const int*   candidates = (const int*)d_in[3];
    const float* atom_embed = (const float*)d_in[4];
    const float* atom_W     = (const float*)d_in[5];
    const float* atom_b     = (const float*)d_in[6];
    const float* conv_W     = (const float*)d_in[10];
    const float* conv_b     = (const float*)d_in[11];
    const float* s_W1       = (const float*)d_in[12];
    const float* s_b1       = (const float*)d_in[13];
    const float* s_W2       = (const float*)d_in[14];
    const float* s_b2       = (const float*)d_in[15];
    float* out = (float*)d_out;

    char* w = (char*)d_ws;
    size_t o = 0;
    auto alloc = [&](size_t bytes) {
        void* p = w + o;
        o += (bytes + 255) & ~(size_t)255;
        return p;
    };
    float*          h0   = (float*)alloc((size_t)N_NODES * HID * 4);
    float*          h1   = (float*)alloc((size_t)N_NODES * HID * 4);
    float*          P    = (float*)alloc((size_t)N_NODES * HID * 4);
    float*          Q    = (float*)alloc((size_t)N_NODES * HID * 4);
    unsigned short* Ah   = (unsigned short*)alloc((size_t)N_NODES * HID * 2);
    unsigned short* Al   = (unsigned short*)alloc((size_t)N_NODES * HID * 2);
    unsigned short* WTh  = (unsigned short*)alloc((size_t)5 * 65536 * 2);
    unsigned short* WTl  = (unsigned short*)alloc((size_t)5 * 65536 * 2);
    float*          E0   = (float*)alloc((size_t)N_ATYPE * HID * 4);
    float*          part = (float*)alloc((size_t)8 * N_CAND * 4);
    int*            ints = (int*)alloc((size_t)3 * N_NODES * 4);
    float*          ns   = (float*)alloc((size_t)N_NODES * 4);
    float*          nd   = (float*)alloc((size_t)N_NODES * 4);
    int*            off  = (int*)alloc((size_t)(N_NODES + 1) * 4);
    int*            csr  = (int*)alloc((size_t)N_EDGES * 4);
    int* dego = ints;
    int* degi = ints + N_NODES;
    int* cur  = ints + 2 * N_NODES;

    hipMemsetAsync(ints, 0, (size_t)3 * N_NODES * 4, stream);

    // E0 = atom_embed @ atom_W + atom_b (fp32, tiny)
    k_gemm<<<dim3(2, 4), 256, 0, stream>>>(atom_embed, atom_W, atom_b, E0, N_ATYPE, 0);
    // weight prep: split-bf16 + transpose (5 mats)
    k_prep_w<<<320, 256, 0, stream>>>(conv_W, s_W1, WTh, WTl);

    k_hist<<<(N_EDGES + 255) / 256, 256, 0, stream>>>(edge_index, dego, degi);
    k_norm<<<(N_NODES + 255) / 256, 256, 0, stream>>>(dego, degi, ns, nd);
    k_h0<<<N_NODES / 4, 256, 0, stream>>>(atom_types, E0, ns, h0);
    k_scan<<<1, 1024, 0, stream>>>(degi, off, N_NODES);
    k_fill<<<(N_EDGES + 255) / 256, 256, 0, stream>>>(edge_index, off, cur, csr);

    const float* hc = h0;
    float* hn = h1;
    for (int i = 0; i < N_MP; ++i) {
        k_agg<<<2048, 256, 0, stream>>>(hc, nd, off, csr, Ah, Al);
        const float* sc = (i < N_MP - 1) ? ns : nullptr;
        k_gemm_conv_mfma<<<2560, 64, 0, stream>>>(
            Ah, Al, WTh + (size_t)i * 65536, WTl + (size_t)i * 65536,
            conv_b + (size_t)i * HID, sc, hn, N_NODES);
        float* t = (float*)hc; hc = hn; hn = t;
    }
    // final h -> split-bf16, then P/Q projection on MFMA
    k_split<<<2500, 256, 0, stream>>>(hc, Ah, Al);
    k_gemm_pq_mfma<<<5120, 64, 0, stream>>>(Ah, Al, WTh, WTl, P, Q, N_NODES);

    k_score_part<<<3128, 256, 0, stream>>>(candidates, P, Q, s_b1, s_W2, part);
    k_sred<<<(N_CAND + 255) / 256, 256, 0, stream>>>(part, s_b2, out);
}